// Round 1
// baseline (749.979 us; speedup 1.0000x reference)
//
#include <hip/hip_runtime.h>

// ---------------------------------------------------------------------------
// MultiheadCosformerAttention: B=4, L=4096, E=1024, H=16, hd=64
//   q = relu(x@Wq^T + bq); k = relu(x@Wk^T + bk); v = x@Wv^T + bv
//   q_ = [q*sin_l, q*cos_l], k_ = [k*sin_l, k*cos_l]   (sin/cos over L)
//   kv[n] = sum_l k_[n,l,:] (x) v[n,l,:]   (128x64 per head n in [0,64))
//   den[n,l] = q_[n,l,:] . (sum_l k_[n,l,:]);  z = 1/max(den, 1e-4)
//   attn = (q_ @ kv) * z  -> merge heads -> @Wo^T + bo
// ---------------------------------------------------------------------------

typedef unsigned short u16;
typedef __attribute__((ext_vector_type(8))) __bf16 bf16x8;
typedef __attribute__((ext_vector_type(4))) float f32x4;

#define PI_HALF 1.57079632679489662f
#define EPS_Z 1e-4f

__device__ __forceinline__ u16 f32_to_bf16(float f) {
    union { float f; unsigned int u; } x; x.f = f;
    unsigned int lsb = (x.u >> 16) & 1u;
    x.u += 0x7fffu + lsb;                 // round-to-nearest-even
    return (u16)(x.u >> 16);
}
__device__ __forceinline__ float bf16_to_f32(u16 u) {
    union { float f; unsigned int u; } x; x.u = ((unsigned int)u) << 16;
    return x.f;
}

typedef __attribute__((address_space(1))) void amdgpu_global_t;
typedef __attribute__((address_space(3))) void amdgpu_lds_t;
__device__ __forceinline__ void async_load16(const u16* g, u16* l) {
    // lane i's 16B land at (wave-uniform) l + i*16  [guide §5]
    __builtin_amdgcn_global_load_lds((amdgpu_global_t*)g, (amdgpu_lds_t*)l, 16, 0, 0);
}

// ---------------------------------------------------------------------------
// fp32 -> bf16 convert (vectorized float4 -> ushort4)
// ---------------------------------------------------------------------------
__global__ __launch_bounds__(256) void cvt_bf16(const float* __restrict__ in,
                                                u16* __restrict__ out, int n4) {
    int i = blockIdx.x * 256 + threadIdx.x;
    if (i >= n4) return;
    float4 f = ((const float4*)in)[i];
    ushort4 o;
    o.x = f32_to_bf16(f.x); o.y = f32_to_bf16(f.y);
    o.z = f32_to_bf16(f.z); o.w = f32_to_bf16(f.w);
    ((ushort4*)out)[i] = o;
}

// ---------------------------------------------------------------------------
// bf16 MFMA GEMM:  C[m,n] = sum_k A[m,k]*Bw[n,k] + bias[n]  (optionally relu)
// A: MxK row-major bf16, Bw: NxK row-major bf16 (torch Linear weight).
// 128x128 tile, BK=32, 4 waves (2x2 of 64x64), mfma_f32_16x16x32_bf16.
// M,N multiples of 128; K multiple of 32 (true for all our shapes).
// ---------------------------------------------------------------------------
template <bool RELU, bool OUT_BF16>
__global__ __launch_bounds__(256) void gemm_bt(const u16* __restrict__ A,
                                               const u16* __restrict__ Bw,
                                               const float* __restrict__ bias,
                                               void* __restrict__ Cout,
                                               int M, int N, int K) {
    __shared__ u16 As[128 * 32];   // [row][k] row-major, 64B rows
    __shared__ u16 Bs[128 * 32];
    const int tid  = threadIdx.x;
    const int wave = tid >> 6;
    const int lane = tid & 63;
    const int quad = lane >> 4;
    const int l15  = lane & 15;
    const long tileM = (long)blockIdx.x * 128;
    const long tileN = (long)blockIdx.y * 128;
    const int wm = (wave >> 1) * 64;
    const int wn = (wave & 1) * 64;
    // staging: wave covers rows [wave*32, wave*32+32); lane i -> row +i/4, k8 = i%4
    const int s_row = wave * 32 + (lane >> 2);
    const int s_col = (lane & 3) * 8;

    const u16* gA = A  + (tileM + s_row) * (long)K + s_col;
    const u16* gB = Bw + (tileN + s_row) * (long)K + s_col;
    u16* lA = &As[wave * 1024];
    u16* lB = &Bs[wave * 1024];

    f32x4 acc[4][4] = {};

    for (int kb = 0; kb < K; kb += 32) {
        async_load16(gA,                lA);
        async_load16(gA + 16 * (long)K, lA + 512);
        async_load16(gB,                lB);
        async_load16(gB + 16 * (long)K, lB + 512);
        gA += 32; gB += 32;
        __syncthreads();   // drains vmcnt (async LDS stores) + barrier
        bf16x8 af[4], bf[4];
#pragma unroll
        for (int i = 0; i < 4; i++) {
            af[i] = *(const bf16x8*)&As[(wm + i * 16 + l15) * 32 + quad * 8];
            bf[i] = *(const bf16x8*)&Bs[(wn + i * 16 + l15) * 32 + quad * 8];
        }
#pragma unroll
        for (int i = 0; i < 4; i++)
#pragma unroll
            for (int j = 0; j < 4; j++)
                acc[i][j] = __builtin_amdgcn_mfma_f32_16x16x32_bf16(
                    af[i], bf[j], acc[i][j], 0, 0, 0);
        __syncthreads();   // all waves done reading before next stage
    }

    // epilogue: D layout col=lane&15 (n), row=quad*4+reg (m)  [m89-verified]
#pragma unroll
    for (int j = 0; j < 4; j++) {
        const long n = tileN + wn + j * 16 + l15;
        const float bv = bias[n];
#pragma unroll
        for (int i = 0; i < 4; i++) {
            const long m0 = tileM + wm + i * 16 + quad * 4;
#pragma unroll
            for (int r = 0; r < 4; r++) {
                float v = acc[i][j][r] + bv;
                if (RELU) v = fmaxf(v, 0.0f);
                if (OUT_BF16)
                    ((u16*)Cout)[(m0 + r) * (long)N + n] = f32_to_bf16(v);
                else
                    ((float*)Cout)[(m0 + r) * (long)N + n] = v;
            }
        }
    }
}

// ---------------------------------------------------------------------------
// Stage C: kv[head][128][64] += sum over L-chunk of k_ (x) v ; ksum[head][128]
// grid (16 chunks, 64 heads), 256 threads. atomicAdd into zeroed ws.
// ---------------------------------------------------------------------------
__global__ __launch_bounds__(256) void kv_accum(const u16* __restrict__ kmat,
                                                const u16* __restrict__ vmat,
                                                float* __restrict__ kvws,
                                                float* __restrict__ ksumws) {
    __shared__ __align__(16) float ks[32][68];
    __shared__ __align__(16) float vs[32][68];
    __shared__ float scs[32], scc[32];
    const int tid = threadIdx.x;
    const int head = blockIdx.y;
    const int b = head >> 4, h = head & 15;
    const int l0 = blockIdx.x * 256;
    const int lt = tid >> 3;      // load row 0..31
    const int g  = tid & 7;       // load col-group 0..7
    const int dp = tid >> 3;      // 0..31  -> dk pair
    const int mg = tid & 7;       // m-group (8 m's)
    const int dk0 = dp * 2, dk1 = dp * 2 + 1;

    float as0[8] = {}, ac0[8] = {}, as1[8] = {}, ac1[8] = {};
    float ks0s = 0.f, ks0c = 0.f, ks1s = 0.f, ks1c = 0.f;

    for (int tile = 0; tile < 8; tile++) {
        const int lbase = l0 + tile * 32;
        {
            const long row = ((long)b * 4096 + lbase + lt) * 1024 + h * 64 + g * 8;
            uint4 kk = *(const uint4*)(kmat + row);
            uint4 vv = *(const uint4*)(vmat + row);
            const u16* kp = (const u16*)&kk;
            const u16* vp = (const u16*)&vv;
#pragma unroll
            for (int j = 0; j < 8; j++) {
                ks[lt][g * 8 + j] = bf16_to_f32(kp[j]);
                vs[lt][g * 8 + j] = bf16_to_f32(vp[j]);
            }
        }
        if (tid < 32) {
            float idx = PI_HALF * (float)(lbase + tid + 1) * (1.0f / 4096.0f);
            scs[tid] = sinf(idx);
            scc[tid] = cosf(idx);
        }
        __syncthreads();
#pragma unroll 4
        for (int l = 0; l < 32; l++) {
            const float sn = scs[l], cs = scc[l];
            const float k0 = ks[l][dk0], k1 = ks[l][dk1];
            const float k0s = k0 * sn, k0c = k0 * cs;
            const float k1s = k1 * sn, k1c = k1 * cs;
            ks0s += k0s; ks0c += k0c; ks1s += k1s; ks1c += k1c;
            const float4 va = *(const float4*)&vs[l][mg * 8];
            const float4 vb = *(const float4*)&vs[l][mg * 8 + 4];
            const float vv8[8] = {va.x, va.y, va.z, va.w, vb.x, vb.y, vb.z, vb.w};
#pragma unroll
            for (int j = 0; j < 8; j++) {
                as0[j] = fmaf(k0s, vv8[j], as0[j]);
                ac0[j] = fmaf(k0c, vv8[j], ac0[j]);
                as1[j] = fmaf(k1s, vv8[j], as1[j]);
                ac1[j] = fmaf(k1c, vv8[j], ac1[j]);
            }
        }
        __syncthreads();
    }
    float* kvh = kvws + (long)head * 128 * 64;
#pragma unroll
    for (int j = 0; j < 8; j++) {
        atomicAdd(&kvh[dk0 * 64 + mg * 8 + j], as0[j]);
        atomicAdd(&kvh[(64 + dk0) * 64 + mg * 8 + j], ac0[j]);
        atomicAdd(&kvh[dk1 * 64 + mg * 8 + j], as1[j]);
        atomicAdd(&kvh[(64 + dk1) * 64 + mg * 8 + j], ac1[j]);
    }
    if (mg == 0) {
        float* ksh = ksumws + head * 128;
        atomicAdd(&ksh[dk0], ks0s);
        atomicAdd(&ksh[64 + dk0], ks0c);
        atomicAdd(&ksh[dk1], ks1s);
        atomicAdd(&ksh[64 + dk1], ks1c);
    }
}

// ---------------------------------------------------------------------------
// Stage D: attn[n,l,m] = (sum_d q_[n,l,d]*kv[n,d,m]) * z ; write merged (B,L,E) bf16
// grid (64 l-chunks of 64, 64 heads), 256 threads = 4 waves, wave handles one l.
// ---------------------------------------------------------------------------
__global__ __launch_bounds__(256) void attn_out(const u16* __restrict__ qmat,
                                                const float* __restrict__ kvws,
                                                const float* __restrict__ ksumws,
                                                u16* __restrict__ merged) {
    __shared__ float kvs[128][68];  // stride 68: lanes hit 2/bank (free)
    __shared__ float kss[128];
    __shared__ float qs[4][64];
    const int tid = threadIdx.x;
    const int w = tid >> 6, lane = tid & 63;
    const int head = blockIdx.y;
    const int b = head >> 4, h = head & 15;
    const int l0 = blockIdx.x * 64;

    const float* kvh = kvws + (long)head * 8192;
    for (int i = tid; i < 8192; i += 256) kvs[i >> 6][i & 63] = kvh[i];
    if (tid < 128) kss[tid] = ksumws[head * 128 + tid];
    __syncthreads();

    for (int t = 0; t < 16; t++) {
        const int l = l0 + t * 4 + w;
        const long qbase = ((long)b * 4096 + l) * 1024 + h * 64;
        const float qv = bf16_to_f32(qmat[qbase + lane]);
        qs[w][lane] = qv;  // intra-wave LDS broadcast (lgkmcnt-ordered)
        const float idx = PI_HALF * (float)(l + 1) * (1.0f / 4096.0f);
        const float sn = sinf(idx), cs = cosf(idx);
        float s1 = 0.f, s2 = 0.f;
#pragma unroll
        for (int dk = 0; dk < 64; dk++) {
            const float q = qs[w][dk];
            s1 = fmaf(q, kvs[dk][lane], s1);
            s2 = fmaf(q, kvs[64 + dk][lane], s2);
        }
        float den = qv * (sn * kss[lane] + cs * kss[64 + lane]);
#pragma unroll
        for (int off = 32; off; off >>= 1) den += __shfl_xor(den, off, 64);
        const float num = sn * s1 + cs * s2;
        const float z = 1.0f / fmaxf(den, EPS_Z);
        merged[qbase + lane] = f32_to_bf16(num * z);
    }
}

// ---------------------------------------------------------------------------
extern "C" void kernel_launch(void* const* d_in, const int* in_sizes, int n_in,
                              void* d_out, int out_size, void* d_ws, size_t ws_size,
                              hipStream_t stream) {
    (void)in_sizes; (void)n_in; (void)out_size; (void)ws_size;
    const float* x  = (const float*)d_in[0];
    const float* Wq = (const float*)d_in[1];
    const float* bq = (const float*)d_in[2];
    const float* Wk = (const float*)d_in[3];
    const float* bk = (const float*)d_in[4];
    const float* Wv = (const float*)d_in[5];
    const float* bv = (const float*)d_in[6];
    const float* Wo = (const float*)d_in[7];
    const float* bo = (const float*)d_in[8];
    float* out = (float*)d_out;

    const int M = 16384, E = 1024;
    char* ws = (char*)d_ws;
    const size_t SZ32 = 33554432;  // 16M bf16
    u16* xb  = (u16*)(ws);                  // 32 MB, reused as merged later
    u16* qb  = (u16*)(ws + SZ32);
    u16* kb  = (u16*)(ws + 2 * SZ32);
    u16* vb  = (u16*)(ws + 3 * SZ32);
    u16* wqb = (u16*)(ws + 4 * SZ32);
    u16* wkb = (u16*)(ws + 4 * SZ32 + 1 * 2097152);
    u16* wvb = (u16*)(ws + 4 * SZ32 + 2 * 2097152);
    u16* wob = (u16*)(ws + 4 * SZ32 + 3 * 2097152);
    float* kvw = (float*)(ws + 4 * SZ32 + 4 * 2097152);
    float* ksw = (float*)(ws + 4 * SZ32 + 4 * 2097152 + 64 * 128 * 64 * 4);
    u16* mergedb = xb;  // x dead after QKV GEMMs

    // zero kv + ksum accumulators (ws is poisoned 0xAA each call)
    hipMemsetAsync(kvw, 0, (size_t)(64 * 128 * 64 + 64 * 128) * sizeof(float), stream);

    cvt_bf16<<<dim3((M * E / 4 + 255) / 256), dim3(256), 0, stream>>>(x, xb, M * E / 4);
    cvt_bf16<<<dim3((E * E / 4 + 255) / 256), dim3(256), 0, stream>>>(Wq, wqb, E * E / 4);
    cvt_bf16<<<dim3((E * E / 4 + 255) / 256), dim3(256), 0, stream>>>(Wk, wkb, E * E / 4);
    cvt_bf16<<<dim3((E * E / 4 + 255) / 256), dim3(256), 0, stream>>>(Wv, wvb, E * E / 4);
    cvt_bf16<<<dim3((E * E / 4 + 255) / 256), dim3(256), 0, stream>>>(Wo, wob, E * E / 4);

    dim3 gg(M / 128, E / 128), bb(256);
    gemm_bt<true,  true><<<gg, bb, 0, stream>>>(xb, wqb, bq, qb, M, E, E);
    gemm_bt<true,  true><<<gg, bb, 0, stream>>>(xb, wkb, bk, kb, M, E, E);
    gemm_bt<false, true><<<gg, bb, 0, stream>>>(xb, wvb, bv, vb, M, E, E);

    kv_accum<<<dim3(16, 64), dim3(256), 0, stream>>>(kb, vb, kvw, ksw);
    attn_out<<<dim3(64, 64), dim3(256), 0, stream>>>(qb, kvw, ksw, mergedb);

    gemm_bt<false, false><<<gg, bb, 0, stream>>>(mergedb, wob, bo, out, M, E, E);
}

// Round 2
// 464.379 us; speedup vs baseline: 1.6150x; 1.6150x over previous
//
#include <hip/hip_runtime.h>

// ---------------------------------------------------------------------------
// MultiheadCosformerAttention: B=4, L=4096, E=1024, H=16, hd=64
// Round 2: (a) kv_accum atomics -> per-chunk partial buffers + reduce
//          (b) attn core -> per-head MFMA GEMM (N=80 augmented with ksum col)
// ---------------------------------------------------------------------------

typedef unsigned short u16;
typedef __attribute__((ext_vector_type(8))) __bf16 bf16x8;
typedef __attribute__((ext_vector_type(4))) float f32x4;

#define PI_HALF 1.57079632679489662f
#define EPS_Z 1e-4f

__device__ __forceinline__ u16 f32_to_bf16(float f) {
    union { float f; unsigned int u; } x; x.f = f;
    unsigned int lsb = (x.u >> 16) & 1u;
    x.u += 0x7fffu + lsb;                 // round-to-nearest-even
    return (u16)(x.u >> 16);
}
__device__ __forceinline__ float bf16_to_f32(u16 u) {
    union { float f; unsigned int u; } x; x.u = ((unsigned int)u) << 16;
    return x.f;
}

typedef __attribute__((address_space(1))) void amdgpu_global_t;
typedef __attribute__((address_space(3))) void amdgpu_lds_t;
__device__ __forceinline__ void async_load16(const u16* g, u16* l) {
    __builtin_amdgcn_global_load_lds((amdgpu_global_t*)g, (amdgpu_lds_t*)l, 16, 0, 0);
}

// ---------------------------------------------------------------------------
// fp32 -> bf16 convert
// ---------------------------------------------------------------------------
__global__ __launch_bounds__(256) void cvt_bf16(const float* __restrict__ in,
                                                u16* __restrict__ out, int n4) {
    int i = blockIdx.x * 256 + threadIdx.x;
    if (i >= n4) return;
    float4 f = ((const float4*)in)[i];
    ushort4 o;
    o.x = f32_to_bf16(f.x); o.y = f32_to_bf16(f.y);
    o.z = f32_to_bf16(f.z); o.w = f32_to_bf16(f.w);
    ((ushort4*)out)[i] = o;
}

// ---------------------------------------------------------------------------
// bf16 MFMA GEMM (m97 structure, verified round 1)
// ---------------------------------------------------------------------------
template <bool RELU, bool OUT_BF16>
__global__ __launch_bounds__(256) void gemm_bt(const u16* __restrict__ A,
                                               const u16* __restrict__ Bw,
                                               const float* __restrict__ bias,
                                               void* __restrict__ Cout,
                                               int M, int N, int K) {
    __shared__ u16 As[128 * 32];
    __shared__ u16 Bs[128 * 32];
    const int tid  = threadIdx.x;
    const int wave = tid >> 6;
    const int lane = tid & 63;
    const int quad = lane >> 4;
    const int l15  = lane & 15;
    const long tileM = (long)blockIdx.x * 128;
    const long tileN = (long)blockIdx.y * 128;
    const int wm = (wave >> 1) * 64;
    const int wn = (wave & 1) * 64;
    const int s_row = wave * 32 + (lane >> 2);
    const int s_col = (lane & 3) * 8;

    const u16* gA = A  + (tileM + s_row) * (long)K + s_col;
    const u16* gB = Bw + (tileN + s_row) * (long)K + s_col;
    u16* lA = &As[wave * 1024];
    u16* lB = &Bs[wave * 1024];

    f32x4 acc[4][4] = {};

    for (int kb = 0; kb < K; kb += 32) {
        async_load16(gA,                lA);
        async_load16(gA + 16 * (long)K, lA + 512);
        async_load16(gB,                lB);
        async_load16(gB + 16 * (long)K, lB + 512);
        gA += 32; gB += 32;
        __syncthreads();
        bf16x8 af[4], bf[4];
#pragma unroll
        for (int i = 0; i < 4; i++) {
            af[i] = *(const bf16x8*)&As[(wm + i * 16 + l15) * 32 + quad * 8];
            bf[i] = *(const bf16x8*)&Bs[(wn + i * 16 + l15) * 32 + quad * 8];
        }
#pragma unroll
        for (int i = 0; i < 4; i++)
#pragma unroll
            for (int j = 0; j < 4; j++)
                acc[i][j] = __builtin_amdgcn_mfma_f32_16x16x32_bf16(
                    af[i], bf[j], acc[i][j], 0, 0, 0);
        __syncthreads();
    }

#pragma unroll
    for (int j = 0; j < 4; j++) {
        const long n = tileN + wn + j * 16 + l15;
        const float bv = bias[n];
#pragma unroll
        for (int i = 0; i < 4; i++) {
            const long m0 = tileM + wm + i * 16 + quad * 4;
#pragma unroll
            for (int r = 0; r < 4; r++) {
                float v = acc[i][j][r] + bv;
                if (RELU) v = fmaxf(v, 0.0f);
                if (OUT_BF16)
                    ((u16*)Cout)[(m0 + r) * (long)N + n] = f32_to_bf16(v);
                else
                    ((float*)Cout)[(m0 + r) * (long)N + n] = v;
            }
        }
    }
}

// ---------------------------------------------------------------------------
// Stage C: per-chunk kv partials, NO cross-block atomics.
// kvp layout [chunk16][head64][dv 64][d2 128] f32 (kv TRANSPOSED: row=dv, col=d2)
// ksp layout [chunk16][head64][128] f32
// grid (16, 64), 256 threads.
// ---------------------------------------------------------------------------
__global__ __launch_bounds__(256) void kv_accum(const u16* __restrict__ kmat,
                                                const u16* __restrict__ vmat,
                                                float* __restrict__ kvp,
                                                float* __restrict__ ksp) {
    __shared__ __align__(16) float ks[32][68];
    __shared__ __align__(16) float vs[32][68];
    __shared__ float scs[32], scc[32];
    const int tid = threadIdx.x;
    const int head = blockIdx.y;
    const int b = head >> 4, h = head & 15;
    const int l0 = blockIdx.x * 256;
    const int lt = tid >> 3;      // staging row 0..31
    const int g  = tid & 7;       // staging col-group
    const int dp = tid & 31;      // dk pair (coalesced partial stores)
    const int mg = tid >> 5;      // dv-group of 8
    const int dk0 = dp * 2;

    float as0[8] = {}, ac0[8] = {}, as1[8] = {}, ac1[8] = {};
    float ks0s = 0.f, ks0c = 0.f, ks1s = 0.f, ks1c = 0.f;

    for (int tile = 0; tile < 8; tile++) {
        const int lbase = l0 + tile * 32;
        {
            const long row = ((long)b * 4096 + lbase + lt) * 1024 + h * 64 + g * 8;
            uint4 kk = *(const uint4*)(kmat + row);
            uint4 vv = *(const uint4*)(vmat + row);
            const u16* kp = (const u16*)&kk;
            const u16* vp = (const u16*)&vv;
#pragma unroll
            for (int j = 0; j < 8; j++) {
                ks[lt][g * 8 + j] = bf16_to_f32(kp[j]);
                vs[lt][g * 8 + j] = bf16_to_f32(vp[j]);
            }
        }
        if (tid < 32) {
            float idx = PI_HALF * (float)(lbase + tid + 1) * (1.0f / 4096.0f);
            scs[tid] = sinf(idx);
            scc[tid] = cosf(idx);
        }
        __syncthreads();
#pragma unroll 4
        for (int l = 0; l < 32; l++) {
            const float sn = scs[l], cs = scc[l];
            const float2 kk = *(const float2*)&ks[l][dk0];
            const float k0s = kk.x * sn, k0c = kk.x * cs;
            const float k1s = kk.y * sn, k1c = kk.y * cs;
            ks0s += k0s; ks0c += k0c; ks1s += k1s; ks1c += k1c;
            const float4 va = *(const float4*)&vs[l][mg * 8];
            const float4 vb = *(const float4*)&vs[l][mg * 8 + 4];
            const float vv8[8] = {va.x, va.y, va.z, va.w, vb.x, vb.y, vb.z, vb.w};
#pragma unroll
            for (int j = 0; j < 8; j++) {
                as0[j] = fmaf(k0s, vv8[j], as0[j]);
                ac0[j] = fmaf(k0c, vv8[j], ac0[j]);
                as1[j] = fmaf(k1s, vv8[j], as1[j]);
                ac1[j] = fmaf(k1c, vv8[j], ac1[j]);
            }
        }
        __syncthreads();
    }
    // store partials: row dv = mg*8+j, cols (dk0,dk0+1) sin and (64+dk0, 64+dk0+1) cos
    float* base = kvp + ((long)blockIdx.x * 64 + head) * 8192;
#pragma unroll
    for (int j = 0; j < 8; j++) {
        float2 s01 = make_float2(as0[j], as1[j]);
        float2 c01 = make_float2(ac0[j], ac1[j]);
        *(float2*)(base + (mg * 8 + j) * 128 + dk0)      = s01;
        *(float2*)(base + (mg * 8 + j) * 128 + 64 + dk0) = c01;
    }
    if (mg == 0) {
        float* kb2 = ksp + ((long)blockIdx.x * 64 + head) * 128;
        *(float2*)(kb2 + dk0)      = make_float2(ks0s, ks1s);
        *(float2*)(kb2 + 64 + dk0) = make_float2(ks0c, ks1c);
    }
}

// ---------------------------------------------------------------------------
// Stage C2: reduce 16 partials -> augmented bf16 B-matrix Bt[head][80][128]
//   rows 0..63: kv^T (row dv, col d2); row 64: ksum[d2]; rows 65..79: zero
// ---------------------------------------------------------------------------
__global__ __launch_bounds__(256) void kv_reduce(const float* __restrict__ kvp,
                                                 const float* __restrict__ ksp,
                                                 u16* __restrict__ Bt) {
    const int idx = blockIdx.x * 256 + threadIdx.x;   // 64*80*128 = 655360
    const int d2 = idx & 127;
    const int n  = (idx >> 7) % 80;
    const int head = idx / (80 * 128);
    float s = 0.0f;
    if (n < 64) {
#pragma unroll
        for (int c = 0; c < 16; c++)
            s += kvp[((long)c * 64 + head) * 8192 + n * 128 + d2];
    } else if (n == 64) {
#pragma unroll
        for (int c = 0; c < 16; c++)
            s += ksp[((long)c * 64 + head) * 128 + d2];
    }
    Bt[(long)head * 10240 + n * 128 + d2] = f32_to_bf16(s);
}

// ---------------------------------------------------------------------------
// Stage D: per-head MFMA GEMM: attn[l, 0..79] = q_[l, 0..127] @ Bt^T
//   col 64 = denominator; scale rows by z and write merged (B,L,E) bf16.
// q_ built on the fly: q_[l][k] = q[l][k&63] * (k<64 ? sin_l : cos_l)
// grid (32 m-tiles of 128, 64 heads), 256 threads = 4 waves (32 rows each).
// LDS padded (stride 72 / 136) -> manual staging (padding breaks async lds).
// ---------------------------------------------------------------------------
__global__ __launch_bounds__(256) void attn_mfma(const u16* __restrict__ qb,
                                                 const u16* __restrict__ Bt,
                                                 u16* __restrict__ merged) {
    __shared__ __align__(16) u16 As[128 * 72];   // q tile [l][64], stride 72
    __shared__ __align__(16) u16 Bs[80 * 136];   // Bt tile [n][128], stride 136
    const int tid = threadIdx.x;
    const int wave = tid >> 6, lane = tid & 63;
    const int quad = lane >> 4, l15 = lane & 15;
    const int head = blockIdx.y;
    const int b = head >> 4, h = head & 15;
    const int tm = blockIdx.x * 128;
    const long b4 = (long)b * 4096;

    // stage A: 128 rows x 64 bf16 (128B) = 1024 16B-chunks
    for (int c = tid; c < 1024; c += 256) {
        const int row = c >> 3, c8 = c & 7;
        uint4 t = *(const uint4*)(qb + (b4 + tm + row) * 1024 + h * 64 + c8 * 8);
        *(uint4*)&As[row * 72 + c8 * 8] = t;
    }
    // stage B: 80 rows x 128 bf16 (256B) = 1280 16B-chunks
    for (int c = tid; c < 1280; c += 256) {
        const int row = c >> 4, c16 = c & 15;
        uint4 t = *(const uint4*)(Bt + (long)head * 10240 + row * 128 + c16 * 8);
        *(uint4*)&Bs[row * 136 + c16 * 8] = t;
    }
    const int wm = wave * 32;
    float snl[2], csl[2];
#pragma unroll
    for (int i = 0; i < 2; i++) {
        const int l = tm + wm + i * 16 + l15;
        const float idx = PI_HALF * (float)(l + 1) * (1.0f / 4096.0f);
        snl[i] = sinf(idx); csl[i] = cosf(idx);
    }
    __syncthreads();

    f32x4 acc[2][5] = {};
#pragma unroll
    for (int kb = 0; kb < 4; kb++) {
        const int qc = (kb & 1) * 32 + quad * 8;
        bf16x8 af[2];
#pragma unroll
        for (int i = 0; i < 2; i++) {
            bf16x8 raw = *(const bf16x8*)&As[(wm + i * 16 + l15) * 72 + qc];
            const float s = (kb < 2) ? snl[i] : csl[i];
            bf16x8 sc;
#pragma unroll
            for (int e = 0; e < 8; e++) sc[e] = (__bf16)((float)raw[e] * s);
            af[i] = sc;
        }
        bf16x8 bf[5];
#pragma unroll
        for (int j = 0; j < 5; j++)
            bf[j] = *(const bf16x8*)&Bs[(j * 16 + l15) * 136 + kb * 32 + quad * 8];
#pragma unroll
        for (int i = 0; i < 2; i++)
#pragma unroll
            for (int j = 0; j < 5; j++)
                acc[i][j] = __builtin_amdgcn_mfma_f32_16x16x32_bf16(
                    af[i], bf[j], acc[i][j], 0, 0, 0);
    }

    // epilogue: den = col 64 (lives at l15==0); z = 1/max(den,eps)
#pragma unroll
    for (int i = 0; i < 2; i++) {
        float z[4];
#pragma unroll
        for (int r = 0; r < 4; r++) {
            const float den = __shfl(acc[i][4][r], lane & 0x30, 64);
            z[r] = 1.0f / fmaxf(den, EPS_Z);
        }
#pragma unroll
        for (int j = 0; j < 4; j++)
#pragma unroll
            for (int r = 0; r < 4; r++) {
                const int l = tm + wm + i * 16 + quad * 4 + r;
                merged[(b4 + l) * 1024 + h * 64 + j * 16 + l15] =
                    f32_to_bf16(acc[i][j][r] * z[r]);
            }
    }
}

// ---------------------------------------------------------------------------
extern "C" void kernel_launch(void* const* d_in, const int* in_sizes, int n_in,
                              void* d_out, int out_size, void* d_ws, size_t ws_size,
                              hipStream_t stream) {
    (void)in_sizes; (void)n_in; (void)out_size; (void)ws_size;
    const float* x  = (const float*)d_in[0];
    const float* Wq = (const float*)d_in[1];
    const float* bq = (const float*)d_in[2];
    const float* Wk = (const float*)d_in[3];
    const float* bk = (const float*)d_in[4];
    const float* Wv = (const float*)d_in[5];
    const float* bv = (const float*)d_in[6];
    const float* Wo = (const float*)d_in[7];
    const float* bo = (const float*)d_in[8];
    float* out = (float*)d_out;

    const int M = 16384, E = 1024;
    char* ws = (char*)d_ws;
    const size_t MB = 1048576;
    u16* xb  = (u16*)(ws);              // 32 MiB; dead after V-GEMM -> kvp
    u16* qb  = (u16*)(ws + 32 * MB);
    u16* kb  = (u16*)(ws + 64 * MB);    // dead after kv_accum -> merged
    u16* vb  = (u16*)(ws + 96 * MB);
    u16* wqb = (u16*)(ws + 128 * MB);
    u16* wkb = (u16*)(ws + 130 * MB);
    u16* wvb = (u16*)(ws + 132 * MB);
    u16* wob = (u16*)(ws + 134 * MB);
    u16* Btb = (u16*)(ws + 136 * MB);   // 1.25 MiB
    float* ksp = (float*)(ws + 138 * MB); // 0.5 MiB
    float* kvp = (float*)xb;            // 16*64*64*128*4 = exactly 32 MiB
    u16* mergedb = kb;

    cvt_bf16<<<dim3((M * E / 4 + 255) / 256), dim3(256), 0, stream>>>(x, xb, M * E / 4);
    cvt_bf16<<<dim3((E * E / 4 + 255) / 256), dim3(256), 0, stream>>>(Wq, wqb, E * E / 4);
    cvt_bf16<<<dim3((E * E / 4 + 255) / 256), dim3(256), 0, stream>>>(Wk, wkb, E * E / 4);
    cvt_bf16<<<dim3((E * E / 4 + 255) / 256), dim3(256), 0, stream>>>(Wv, wvb, E * E / 4);
    cvt_bf16<<<dim3((E * E / 4 + 255) / 256), dim3(256), 0, stream>>>(Wo, wob, E * E / 4);

    dim3 gg(M / 128, E / 128), bb(256);
    gemm_bt<true,  true><<<gg, bb, 0, stream>>>(xb, wqb, bq, qb, M, E, E);
    gemm_bt<true,  true><<<gg, bb, 0, stream>>>(xb, wkb, bk, kb, M, E, E);
    gemm_bt<false, true><<<gg, bb, 0, stream>>>(xb, wvb, bv, vb, M, E, E);

    kv_accum<<<dim3(16, 64), dim3(256), 0, stream>>>(kb, vb, kvp, ksp);
    kv_reduce<<<dim3(2560), dim3(256), 0, stream>>>(kvp, ksp, Btb);
    attn_mfma<<<dim3(32, 64), dim3(256), 0, stream>>>(qb, Btb, mergedb);

    gemm_bt<false, false><<<gg, bb, 0, stream>>>(mergedb, wob, bo, out, M, E, E);
}

// Round 3
// 410.713 us; speedup vs baseline: 1.8260x; 1.1307x over previous
//
#include <hip/hip_runtime.h>

// ---------------------------------------------------------------------------
// MultiheadCosformerAttention: B=4, L=4096, E=1024, H=16, hd=64
// Round 3: (a) kv_accum 32 chunks (occupancy 4->8 blocks/CU), bf16 partials
//          (b) QKV projections fused into one N=3072 GEMM (one tail, not 3)
//          (c) weight cvts fused into one launch
// ---------------------------------------------------------------------------

typedef unsigned short u16;
typedef unsigned int u32;
typedef __attribute__((ext_vector_type(8))) __bf16 bf16x8;
typedef __attribute__((ext_vector_type(4))) float f32x4;

#define PI_HALF 1.57079632679489662f
#define EPS_Z 1e-4f

__device__ __forceinline__ u16 f32_to_bf16(float f) {
    union { float f; unsigned int u; } x; x.f = f;
    unsigned int lsb = (x.u >> 16) & 1u;
    x.u += 0x7fffu + lsb;                 // round-to-nearest-even
    return (u16)(x.u >> 16);
}
__device__ __forceinline__ float bf16_to_f32(u16 u) {
    union { float f; unsigned int u; } x; x.u = ((unsigned int)u) << 16;
    return x.f;
}

typedef __attribute__((address_space(1))) void amdgpu_global_t;
typedef __attribute__((address_space(3))) void amdgpu_lds_t;
__device__ __forceinline__ void async_load16(const u16* g, u16* l) {
    __builtin_amdgcn_global_load_lds((amdgpu_global_t*)g, (amdgpu_lds_t*)l, 16, 0, 0);
}

// ---------------------------------------------------------------------------
// fp32 -> bf16 converts
// ---------------------------------------------------------------------------
__global__ __launch_bounds__(256) void cvt_bf16(const float* __restrict__ in,
                                                u16* __restrict__ out, int n4) {
    int i = blockIdx.x * 256 + threadIdx.x;
    if (i >= n4) return;
    float4 f = ((const float4*)in)[i];
    ushort4 o;
    o.x = f32_to_bf16(f.x); o.y = f32_to_bf16(f.y);
    o.z = f32_to_bf16(f.z); o.w = f32_to_bf16(f.w);
    ((ushort4*)out)[i] = o;
}

// 4 weight matrices (E*E each) in one launch; outputs contiguous in wcat.
__global__ __launch_bounds__(256) void cvt_w4(const float* __restrict__ w0,
                                              const float* __restrict__ w1,
                                              const float* __restrict__ w2,
                                              const float* __restrict__ w3,
                                              u16* __restrict__ wcat) {
    const float* src = (blockIdx.y == 0) ? w0 : (blockIdx.y == 1) ? w1
                     : (blockIdx.y == 2) ? w2 : w3;
    u16* dst = wcat + (size_t)blockIdx.y * 1048576;
    int i = blockIdx.x * 256 + threadIdx.x;   // 262144 float4-groups
    float4 f = ((const float4*)src)[i];
    ushort4 o;
    o.x = f32_to_bf16(f.x); o.y = f32_to_bf16(f.y);
    o.z = f32_to_bf16(f.z); o.w = f32_to_bf16(f.w);
    ((ushort4*)dst)[i] = o;
}

// ---------------------------------------------------------------------------
// Fused QKV GEMM: Wcat is [3072][1024] (Wq;Wk;Wv). blockIdx.y in [0,24).
// mat = y>>3 selects {q,k,v} output, bias, relu. m97 K-loop structure.
// ---------------------------------------------------------------------------
__global__ __launch_bounds__(256) void gemm_qkv(const u16* __restrict__ A,
                                                const u16* __restrict__ Wcat,
                                                const float* __restrict__ bq,
                                                const float* __restrict__ bk,
                                                const float* __restrict__ bv,
                                                u16* __restrict__ qo,
                                                u16* __restrict__ ko,
                                                u16* __restrict__ vo) {
    __shared__ u16 As[128 * 32];
    __shared__ u16 Bs[128 * 32];
    const int K = 1024;
    const int tid  = threadIdx.x;
    const int wave = tid >> 6;
    const int lane = tid & 63;
    const int quad = lane >> 4;
    const int l15  = lane & 15;
    const long tileM = (long)blockIdx.x * 128;
    const long tileN = (long)blockIdx.y * 128;
    const int mat = blockIdx.y >> 3;
    const float* bias = (mat == 0) ? bq : (mat == 1) ? bk : bv;
    u16* outp = (mat == 0) ? qo : (mat == 1) ? ko : vo;
    const bool relu = (mat < 2);
    const int wm = (wave >> 1) * 64;
    const int wn = (wave & 1) * 64;
    const int s_row = wave * 32 + (lane >> 2);
    const int s_col = (lane & 3) * 8;

    const u16* gA = A    + (tileM + s_row) * (long)K + s_col;
    const u16* gB = Wcat + (tileN + s_row) * (long)K + s_col;
    u16* lA = &As[wave * 1024];
    u16* lB = &Bs[wave * 1024];

    f32x4 acc[4][4] = {};

    for (int kb = 0; kb < K; kb += 32) {
        async_load16(gA,                lA);
        async_load16(gA + 16 * (long)K, lA + 512);
        async_load16(gB,                lB);
        async_load16(gB + 16 * (long)K, lB + 512);
        gA += 32; gB += 32;
        __syncthreads();
        bf16x8 af[4], bf[4];
#pragma unroll
        for (int i = 0; i < 4; i++) {
            af[i] = *(const bf16x8*)&As[(wm + i * 16 + l15) * 32 + quad * 8];
            bf[i] = *(const bf16x8*)&Bs[(wn + i * 16 + l15) * 32 + quad * 8];
        }
#pragma unroll
        for (int i = 0; i < 4; i++)
#pragma unroll
            for (int j = 0; j < 4; j++)
                acc[i][j] = __builtin_amdgcn_mfma_f32_16x16x32_bf16(
                    af[i], bf[j], acc[i][j], 0, 0, 0);
        __syncthreads();
    }

#pragma unroll
    for (int j = 0; j < 4; j++) {
        const long n = tileN + wn + j * 16 + l15;
        const int nl = (int)n & 1023;
        const float bv_ = bias[nl];
#pragma unroll
        for (int i = 0; i < 4; i++) {
            const long m0 = tileM + wm + i * 16 + quad * 4;
#pragma unroll
            for (int r = 0; r < 4; r++) {
                float v = acc[i][j][r] + bv_;
                if (relu) v = fmaxf(v, 0.0f);
                outp[(m0 + r) * 1024 + nl] = f32_to_bf16(v);
            }
        }
    }
}

// ---------------------------------------------------------------------------
// Output-projection GEMM (fp32 out), m97 structure.
// ---------------------------------------------------------------------------
__global__ __launch_bounds__(256) void gemm_o(const u16* __restrict__ A,
                                              const u16* __restrict__ Bw,
                                              const float* __restrict__ bias,
                                              float* __restrict__ Cout,
                                              int M, int N, int K) {
    __shared__ u16 As[128 * 32];
    __shared__ u16 Bs[128 * 32];
    const int tid  = threadIdx.x;
    const int wave = tid >> 6;
    const int lane = tid & 63;
    const int quad = lane >> 4;
    const int l15  = lane & 15;
    const long tileM = (long)blockIdx.x * 128;
    const long tileN = (long)blockIdx.y * 128;
    const int wm = (wave >> 1) * 64;
    const int wn = (wave & 1) * 64;
    const int s_row = wave * 32 + (lane >> 2);
    const int s_col = (lane & 3) * 8;

    const u16* gA = A  + (tileM + s_row) * (long)K + s_col;
    const u16* gB = Bw + (tileN + s_row) * (long)K + s_col;
    u16* lA = &As[wave * 1024];
    u16* lB = &Bs[wave * 1024];

    f32x4 acc[4][4] = {};

    for (int kb = 0; kb < K; kb += 32) {
        async_load16(gA,                lA);
        async_load16(gA + 16 * (long)K, lA + 512);
        async_load16(gB,                lB);
        async_load16(gB + 16 * (long)K, lB + 512);
        gA += 32; gB += 32;
        __syncthreads();
        bf16x8 af[4], bf[4];
#pragma unroll
        for (int i = 0; i < 4; i++) {
            af[i] = *(const bf16x8*)&As[(wm + i * 16 + l15) * 32 + quad * 8];
            bf[i] = *(const bf16x8*)&Bs[(wn + i * 16 + l15) * 32 + quad * 8];
        }
#pragma unroll
        for (int i = 0; i < 4; i++)
#pragma unroll
            for (int j = 0; j < 4; j++)
                acc[i][j] = __builtin_amdgcn_mfma_f32_16x16x32_bf16(
                    af[i], bf[j], acc[i][j], 0, 0, 0);
        __syncthreads();
    }

#pragma unroll
    for (int j = 0; j < 4; j++) {
        const long n = tileN + wn + j * 16 + l15;
        const float bv = bias[n];
#pragma unroll
        for (int i = 0; i < 4; i++) {
            const long m0 = tileM + wm + i * 16 + quad * 4;
#pragma unroll
            for (int r = 0; r < 4; r++)
                Cout[(m0 + r) * (long)N + n] = acc[i][j][r] + bv;
        }
    }
}

// ---------------------------------------------------------------------------
// Stage C: per-chunk kv partials (bf16), 32 chunks of 128 l's -> 8 blocks/CU.
// kvp layout [chunk32][head64][dv 64][d2 128] bf16 (kv^T: row=dv, col=d2)
// ksp layout [chunk32][head64][128] f32
// ---------------------------------------------------------------------------
__global__ __launch_bounds__(256) void kv_accum(const u16* __restrict__ kmat,
                                                const u16* __restrict__ vmat,
                                                u16* __restrict__ kvp,
                                                float* __restrict__ ksp) {
    __shared__ __align__(16) float ks[32][68];
    __shared__ __align__(16) float vs[32][68];
    __shared__ float scs[32], scc[32];
    const int tid = threadIdx.x;
    const int head = blockIdx.y;
    const int b = head >> 4, h = head & 15;
    const int l0 = blockIdx.x * 128;
    const int lt = tid >> 3;      // staging row 0..31
    const int g  = tid & 7;       // staging col-group
    const int dp = tid & 31;      // dk pair (coalesced partial stores)
    const int mg = tid >> 5;      // dv-group of 8
    const int dk0 = dp * 2;

    float as0[8] = {}, ac0[8] = {}, as1[8] = {}, ac1[8] = {};
    float ks0s = 0.f, ks0c = 0.f, ks1s = 0.f, ks1c = 0.f;

    for (int tile = 0; tile < 4; tile++) {
        const int lbase = l0 + tile * 32;
        {
            const long row = ((long)b * 4096 + lbase + lt) * 1024 + h * 64 + g * 8;
            uint4 kk = *(const uint4*)(kmat + row);
            uint4 vv = *(const uint4*)(vmat + row);
            const u16* kp = (const u16*)&kk;
            const u16* vp = (const u16*)&vv;
#pragma unroll
            for (int j = 0; j < 8; j++) {
                ks[lt][g * 8 + j] = bf16_to_f32(kp[j]);
                vs[lt][g * 8 + j] = bf16_to_f32(vp[j]);
            }
        }
        if (tid < 32) {
            float idx = PI_HALF * (float)(lbase + tid + 1) * (1.0f / 4096.0f);
            scs[tid] = sinf(idx);
            scc[tid] = cosf(idx);
        }
        __syncthreads();
#pragma unroll 4
        for (int l = 0; l < 32; l++) {
            const float sn = scs[l], cs = scc[l];
            const float2 kk = *(const float2*)&ks[l][dk0];
            const float k0s = kk.x * sn, k0c = kk.x * cs;
            const float k1s = kk.y * sn, k1c = kk.y * cs;
            ks0s += k0s; ks0c += k0c; ks1s += k1s; ks1c += k1c;
            const float4 va = *(const float4*)&vs[l][mg * 8];
            const float4 vb = *(const float4*)&vs[l][mg * 8 + 4];
            const float vv8[8] = {va.x, va.y, va.z, va.w, vb.x, vb.y, vb.z, vb.w};
#pragma unroll
            for (int j = 0; j < 8; j++) {
                as0[j] = fmaf(k0s, vv8[j], as0[j]);
                ac0[j] = fmaf(k0c, vv8[j], ac0[j]);
                as1[j] = fmaf(k1s, vv8[j], as1[j]);
                ac1[j] = fmaf(k1c, vv8[j], ac1[j]);
            }
        }
        __syncthreads();
    }
    // store bf16 partials: row dv = mg*8+j; cols (dk0,dk0+1) sin, (+64) cos
    u16* base = kvp + ((long)blockIdx.x * 64 + head) * 8192;
#pragma unroll
    for (int j = 0; j < 8; j++) {
        u32 s01 = (u32)f32_to_bf16(as0[j]) | ((u32)f32_to_bf16(as1[j]) << 16);
        u32 c01 = (u32)f32_to_bf16(ac0[j]) | ((u32)f32_to_bf16(ac1[j]) << 16);
        *(u32*)(base + (mg * 8 + j) * 128 + dk0)      = s01;
        *(u32*)(base + (mg * 8 + j) * 128 + 64 + dk0) = c01;
    }
    if (mg == 0) {
        float* kb2 = ksp + ((long)blockIdx.x * 64 + head) * 128;
        *(float2*)(kb2 + dk0)      = make_float2(ks0s, ks1s);
        *(float2*)(kb2 + 64 + dk0) = make_float2(ks0c, ks1c);
    }
}

// ---------------------------------------------------------------------------
// Stage C2: reduce 32 partials -> augmented bf16 B-matrix Bt[head][80][128]
// ---------------------------------------------------------------------------
__global__ __launch_bounds__(256) void kv_reduce(const u16* __restrict__ kvp,
                                                 const float* __restrict__ ksp,
                                                 u16* __restrict__ Bt) {
    const int idx = blockIdx.x * 256 + threadIdx.x;   // 64*80*128 = 655360
    const int d2 = idx & 127;
    const int n  = (idx >> 7) % 80;
    const int head = idx / (80 * 128);
    float s = 0.0f;
    if (n < 64) {
#pragma unroll
        for (int c = 0; c < 32; c++)
            s += bf16_to_f32(kvp[((long)c * 64 + head) * 8192 + n * 128 + d2]);
    } else if (n == 64) {
#pragma unroll
        for (int c = 0; c < 32; c++)
            s += ksp[((long)c * 64 + head) * 128 + d2];
    }
    Bt[(long)head * 10240 + n * 128 + d2] = f32_to_bf16(s);
}

// ---------------------------------------------------------------------------
// Stage D: per-head MFMA GEMM: attn[l, 0..79] = q_[l, 0..127] @ Bt^T
// ---------------------------------------------------------------------------
__global__ __launch_bounds__(256) void attn_mfma(const u16* __restrict__ qb,
                                                 const u16* __restrict__ Bt,
                                                 u16* __restrict__ merged) {
    __shared__ __align__(16) u16 As[128 * 72];   // q tile [l][64], stride 72
    __shared__ __align__(16) u16 Bs[80 * 136];   // Bt tile [n][128], stride 136
    const int tid = threadIdx.x;
    const int wave = tid >> 6, lane = tid & 63;
    const int quad = lane >> 4, l15 = lane & 15;
    const int head = blockIdx.y;
    const int b = head >> 4, h = head & 15;
    const int tm = blockIdx.x * 128;
    const long b4 = (long)b * 4096;

    for (int c = tid; c < 1024; c += 256) {
        const int row = c >> 3, c8 = c & 7;
        uint4 t = *(const uint4*)(qb + (b4 + tm + row) * 1024 + h * 64 + c8 * 8);
        *(uint4*)&As[row * 72 + c8 * 8] = t;
    }
    for (int c = tid; c < 1280; c += 256) {
        const int row = c >> 4, c16 = c & 15;
        uint4 t = *(const uint4*)(Bt + (long)head * 10240 + row * 128 + c16 * 8);
        *(uint4*)&Bs[row * 136 + c16 * 8] = t;
    }
    const int wm = wave * 32;
    float snl[2], csl[2];
#pragma unroll
    for (int i = 0; i < 2; i++) {
        const int l = tm + wm + i * 16 + l15;
        const float idx = PI_HALF * (float)(l + 1) * (1.0f / 4096.0f);
        snl[i] = sinf(idx); csl[i] = cosf(idx);
    }
    __syncthreads();

    f32x4 acc[2][5] = {};
#pragma unroll
    for (int kb = 0; kb < 4; kb++) {
        const int qc = (kb & 1) * 32 + quad * 8;
        bf16x8 af[2];
#pragma unroll
        for (int i = 0; i < 2; i++) {
            bf16x8 raw = *(const bf16x8*)&As[(wm + i * 16 + l15) * 72 + qc];
            const float s = (kb < 2) ? snl[i] : csl[i];
            bf16x8 sc;
#pragma unroll
            for (int e = 0; e < 8; e++) sc[e] = (__bf16)((float)raw[e] * s);
            af[i] = sc;
        }
        bf16x8 bf[5];
#pragma unroll
        for (int j = 0; j < 5; j++)
            bf[j] = *(const bf16x8*)&Bs[(j * 16 + l15) * 136 + kb * 32 + quad * 8];
#pragma unroll
        for (int i = 0; i < 2; i++)
#pragma unroll
            for (int j = 0; j < 5; j++)
                acc[i][j] = __builtin_amdgcn_mfma_f32_16x16x32_bf16(
                    af[i], bf[j], acc[i][j], 0, 0, 0);
    }

#pragma unroll
    for (int i = 0; i < 2; i++) {
        float z[4];
#pragma unroll
        for (int r = 0; r < 4; r++) {
            const float den = __shfl(acc[i][4][r], lane & 0x30, 64);
            z[r] = 1.0f / fmaxf(den, EPS_Z);
        }
#pragma unroll
        for (int j = 0; j < 4; j++)
#pragma unroll
            for (int r = 0; r < 4; r++) {
                const int l = tm + wm + i * 16 + quad * 4 + r;
                merged[(b4 + l) * 1024 + h * 64 + j * 16 + l15] =
                    f32_to_bf16(acc[i][j][r] * z[r]);
            }
    }
}

// ---------------------------------------------------------------------------
extern "C" void kernel_launch(void* const* d_in, const int* in_sizes, int n_in,
                              void* d_out, int out_size, void* d_ws, size_t ws_size,
                              hipStream_t stream) {
    (void)in_sizes; (void)n_in; (void)out_size; (void)ws_size;
    const float* x  = (const float*)d_in[0];
    const float* Wq = (const float*)d_in[1];
    const float* bq = (const float*)d_in[2];
    const float* Wk = (const float*)d_in[3];
    const float* bk = (const float*)d_in[4];
    const float* Wv = (const float*)d_in[5];
    const float* bv = (const float*)d_in[6];
    const float* Wo = (const float*)d_in[7];
    const float* bo = (const float*)d_in[8];
    float* out = (float*)d_out;

    const int M = 16384, E = 1024;
    char* ws = (char*)d_ws;
    const size_t MB = 1048576;
    u16* xb   = (u16*)(ws);              // 32 MiB; dead after QKV GEMM -> kvp
    u16* qb   = (u16*)(ws + 32 * MB);
    u16* kb   = (u16*)(ws + 64 * MB);    // dead after kv_accum -> merged
    u16* vb   = (u16*)(ws + 96 * MB);
    u16* wcat = (u16*)(ws + 128 * MB);   // Wq;Wk;Wv;Wo bf16, 8 MiB
    u16* wob  = wcat + 3 * (size_t)E * E;
    u16* Btb  = (u16*)(ws + 136 * MB);   // 1.25 MiB
    float* ksp = (float*)(ws + 136 * MB + 1310720 + 2048);  // 1 MiB
    u16* kvp  = xb;                      // 32ch*64h*8192 bf16 = exactly 32 MiB
    u16* mergedb = kb;

    cvt_bf16<<<dim3(M * E / 4 / 256), dim3(256), 0, stream>>>(x, xb, M * E / 4);
    cvt_w4<<<dim3(E * E / 4 / 256, 4), dim3(256), 0, stream>>>(Wq, Wk, Wv, Wo, wcat);

    gemm_qkv<<<dim3(M / 128, 24), dim3(256), 0, stream>>>(xb, wcat, bq, bk, bv,
                                                          qb, kb, vb);

    kv_accum<<<dim3(32, 64), dim3(256), 0, stream>>>(kb, vb, kvp, ksp);
    kv_reduce<<<dim3(2560), dim3(256), 0, stream>>>(kvp, ksp, Btb);
    attn_mfma<<<dim3(32, 64), dim3(256), 0, stream>>>(qb, Btb, mergedb);

    gemm_o<<<dim3(M / 128, E / 128), dim3(256), 0, stream>>>(mergedb, wob, bo,
                                                             out, M, E, E);
}

// Round 4
// 383.987 us; speedup vs baseline: 1.9531x; 1.0696x over previous
//
#include <hip/hip_runtime.h>

// ---------------------------------------------------------------------------
// MultiheadCosformerAttention: B=4, L=4096, E=1024, H=16, hd=64
// Round 4: kv outer-product moved from fp32 VALU (55+ us floor at 157 TF)
//          to bf16 MFMA (k_^T @ [v | 1] per head), transposed LDS staging
//          with XOR bank swizzle + sin/cos register rotation recurrence.
// ---------------------------------------------------------------------------

typedef unsigned short u16;
typedef unsigned int u32;
typedef __attribute__((ext_vector_type(8))) __bf16 bf16x8;
typedef __attribute__((ext_vector_type(4))) float f32x4;

#define PI_HALF 1.57079632679489662f
#define EPS_Z 1e-4f

__device__ __forceinline__ u16 f32_to_bf16(float f) {
    union { float f; unsigned int u; } x; x.f = f;
    unsigned int lsb = (x.u >> 16) & 1u;
    x.u += 0x7fffu + lsb;                 // round-to-nearest-even
    return (u16)(x.u >> 16);
}
__device__ __forceinline__ float bf16_to_f32(u16 u) {
    union { float f; unsigned int u; } x; x.u = ((unsigned int)u) << 16;
    return x.f;
}

typedef __attribute__((address_space(1))) void amdgpu_global_t;
typedef __attribute__((address_space(3))) void amdgpu_lds_t;
__device__ __forceinline__ void async_load16(const u16* g, u16* l) {
    __builtin_amdgcn_global_load_lds((amdgpu_global_t*)g, (amdgpu_lds_t*)l, 16, 0, 0);
}

// ---------------------------------------------------------------------------
// fp32 -> bf16 converts
// ---------------------------------------------------------------------------
__global__ __launch_bounds__(256) void cvt_bf16(const float* __restrict__ in,
                                                u16* __restrict__ out, int n4) {
    int i = blockIdx.x * 256 + threadIdx.x;
    if (i >= n4) return;
    float4 f = ((const float4*)in)[i];
    ushort4 o;
    o.x = f32_to_bf16(f.x); o.y = f32_to_bf16(f.y);
    o.z = f32_to_bf16(f.z); o.w = f32_to_bf16(f.w);
    ((ushort4*)out)[i] = o;
}

__global__ __launch_bounds__(256) void cvt_w4(const float* __restrict__ w0,
                                              const float* __restrict__ w1,
                                              const float* __restrict__ w2,
                                              const float* __restrict__ w3,
                                              u16* __restrict__ wcat) {
    const float* src = (blockIdx.y == 0) ? w0 : (blockIdx.y == 1) ? w1
                     : (blockIdx.y == 2) ? w2 : w3;
    u16* dst = wcat + (size_t)blockIdx.y * 1048576;
    int i = blockIdx.x * 256 + threadIdx.x;
    float4 f = ((const float4*)src)[i];
    ushort4 o;
    o.x = f32_to_bf16(f.x); o.y = f32_to_bf16(f.y);
    o.z = f32_to_bf16(f.z); o.w = f32_to_bf16(f.w);
    ((ushort4*)dst)[i] = o;
}

// ---------------------------------------------------------------------------
// Fused QKV GEMM (m97 structure). Wcat = [3072][1024] (Wq;Wk;Wv).
// ---------------------------------------------------------------------------
__global__ __launch_bounds__(256) void gemm_qkv(const u16* __restrict__ A,
                                                const u16* __restrict__ Wcat,
                                                const float* __restrict__ bq,
                                                const float* __restrict__ bk,
                                                const float* __restrict__ bv,
                                                u16* __restrict__ qo,
                                                u16* __restrict__ ko,
                                                u16* __restrict__ vo) {
    __shared__ u16 As[128 * 32];
    __shared__ u16 Bs[128 * 32];
    const int K = 1024;
    const int tid  = threadIdx.x;
    const int wave = tid >> 6;
    const int lane = tid & 63;
    const int quad = lane >> 4;
    const int l15  = lane & 15;
    const long tileM = (long)blockIdx.x * 128;
    const long tileN = (long)blockIdx.y * 128;
    const int mat = blockIdx.y >> 3;
    const float* bias = (mat == 0) ? bq : (mat == 1) ? bk : bv;
    u16* outp = (mat == 0) ? qo : (mat == 1) ? ko : vo;
    const bool relu = (mat < 2);
    const int wm = (wave >> 1) * 64;
    const int wn = (wave & 1) * 64;
    const int s_row = wave * 32 + (lane >> 2);
    const int s_col = (lane & 3) * 8;

    const u16* gA = A    + (tileM + s_row) * (long)K + s_col;
    const u16* gB = Wcat + (tileN + s_row) * (long)K + s_col;
    u16* lA = &As[wave * 1024];
    u16* lB = &Bs[wave * 1024];

    f32x4 acc[4][4] = {};

    for (int kb = 0; kb < K; kb += 32) {
        async_load16(gA,                lA);
        async_load16(gA + 16 * (long)K, lA + 512);
        async_load16(gB,                lB);
        async_load16(gB + 16 * (long)K, lB + 512);
        gA += 32; gB += 32;
        __syncthreads();
        bf16x8 af[4], bf[4];
#pragma unroll
        for (int i = 0; i < 4; i++) {
            af[i] = *(const bf16x8*)&As[(wm + i * 16 + l15) * 32 + quad * 8];
            bf[i] = *(const bf16x8*)&Bs[(wn + i * 16 + l15) * 32 + quad * 8];
        }
#pragma unroll
        for (int i = 0; i < 4; i++)
#pragma unroll
            for (int j = 0; j < 4; j++)
                acc[i][j] = __builtin_amdgcn_mfma_f32_16x16x32_bf16(
                    af[i], bf[j], acc[i][j], 0, 0, 0);
        __syncthreads();
    }

#pragma unroll
    for (int j = 0; j < 4; j++) {
        const long n = tileN + wn + j * 16 + l15;
        const int nl = (int)n & 1023;
        const float bv_ = bias[nl];
#pragma unroll
        for (int i = 0; i < 4; i++) {
            const long m0 = tileM + wm + i * 16 + quad * 4;
#pragma unroll
            for (int r = 0; r < 4; r++) {
                float v = acc[i][j][r] + bv_;
                if (relu) v = fmaxf(v, 0.0f);
                outp[(m0 + r) * 1024 + nl] = f32_to_bf16(v);
            }
        }
    }
}

// ---------------------------------------------------------------------------
// Output-projection GEMM (fp32 out), m97 structure.
// ---------------------------------------------------------------------------
__global__ __launch_bounds__(256) void gemm_o(const u16* __restrict__ A,
                                              const u16* __restrict__ Bw,
                                              const float* __restrict__ bias,
                                              float* __restrict__ Cout,
                                              int M, int N, int K) {
    __shared__ u16 As[128 * 32];
    __shared__ u16 Bs[128 * 32];
    const int tid  = threadIdx.x;
    const int wave = tid >> 6;
    const int lane = tid & 63;
    const int quad = lane >> 4;
    const int l15  = lane & 15;
    const long tileM = (long)blockIdx.x * 128;
    const long tileN = (long)blockIdx.y * 128;
    const int wm = (wave >> 1) * 64;
    const int wn = (wave & 1) * 64;
    const int s_row = wave * 32 + (lane >> 2);
    const int s_col = (lane & 3) * 8;

    const u16* gA = A  + (tileM + s_row) * (long)K + s_col;
    const u16* gB = Bw + (tileN + s_row) * (long)K + s_col;
    u16* lA = &As[wave * 1024];
    u16* lB = &Bs[wave * 1024];

    f32x4 acc[4][4] = {};

    for (int kb = 0; kb < K; kb += 32) {
        async_load16(gA,                lA);
        async_load16(gA + 16 * (long)K, lA + 512);
        async_load16(gB,                lB);
        async_load16(gB + 16 * (long)K, lB + 512);
        gA += 32; gB += 32;
        __syncthreads();
        bf16x8 af[4], bf[4];
#pragma unroll
        for (int i = 0; i < 4; i++) {
            af[i] = *(const bf16x8*)&As[(wm + i * 16 + l15) * 32 + quad * 8];
            bf[i] = *(const bf16x8*)&Bs[(wn + i * 16 + l15) * 32 + quad * 8];
        }
#pragma unroll
        for (int i = 0; i < 4; i++)
#pragma unroll
            for (int j = 0; j < 4; j++)
                acc[i][j] = __builtin_amdgcn_mfma_f32_16x16x32_bf16(
                    af[i], bf[j], acc[i][j], 0, 0, 0);
        __syncthreads();
    }

#pragma unroll
    for (int j = 0; j < 4; j++) {
        const long n = tileN + wn + j * 16 + l15;
        const float bv = bias[n];
#pragma unroll
        for (int i = 0; i < 4; i++) {
            const long m0 = tileM + wm + i * 16 + quad * 4;
#pragma unroll
            for (int r = 0; r < 4; r++)
                Cout[(m0 + r) * (long)N + n] = acc[i][j][r] + bv;
        }
    }
}

// ---------------------------------------------------------------------------
// Stage C (MFMA): per (chunk, head): part[d2=128][n=80] = k_^T @ [v | 1 | 0]
//   over K = 512 l's. k_[l][d2] = k[l][d2&63]*(d2<64 ? sin_l : cos_l).
//   A-frag rows d2 staged transposed in LDS ([d][l], XOR col swizzle);
//   sin/cos per k-element kept in registers, rotated by pi/256 per k-tile.
// grid (8, 64), 256 threads = 4 waves; wave w: m-rows [w*32, w*32+32),
//   k-rows (w&1)*32.., scale = (w>=2 ? cos : sin).
// part layout: [chunk8][head64][128][80] f32.
// ---------------------------------------------------------------------------
__global__ __launch_bounds__(256) void kv_mfma(const u16* __restrict__ kmat,
                                               const u16* __restrict__ vmat,
                                               float* __restrict__ part) {
    __shared__ u16 Ak[64 * 40];   // [d 64][l 32 +8 pad], stride 80B (16B-mult)
    __shared__ u16 Bv[64 * 40];
    const int tid = threadIdx.x;
    const int wave = tid >> 6, lane = tid & 63;
    const int quad = lane >> 4, l15 = lane & 15;
    const int head = blockIdx.y;
    const int b = head >> 4, h = head & 15;
    const int l0 = blockIdx.x * 512;
    const int sl = tid >> 3;          // staging row l 0..31
    const int sc8 = tid & 7;          // staging d-octet 0..7
    const int scol = sl ^ ((sc8 & 3) << 3);   // XOR swizzle col
    const int krow_base = (wave & 1) * 32;
    const bool use_cos = (wave >> 1) != 0;
    const int mbase = wave * 32;

    // sin/cos for l = l0 + kt*32 + quad*8 + e, advanced by rotation each tile
    float sv[8], cv[8];
#pragma unroll
    for (int e = 0; e < 8; e++) {
        float ang = (PI_HALF / 4096.0f) * (float)(l0 + quad * 8 + e + 1);
        sv[e] = sinf(ang); cv[e] = cosf(ang);
    }
    const float cD = 0.9999247018391445f;   // cos(pi/256)
    const float sD = 0.0122715382857199f;   // sin(pi/256)

    bf16x8 onesf;
#pragma unroll
    for (int e = 0; e < 8; e++)
        onesf[e] = (l15 == 0) ? (__bf16)1.0f : (__bf16)0.0f;

    f32x4 acc[2][5] = {};

    for (int kt = 0; kt < 16; kt++) {
        const long row = ((long)b * 4096 + l0 + kt * 32 + sl) * 1024 + h * 64 + sc8 * 8;
        uint4 kk = *(const uint4*)(kmat + row);
        uint4 vv = *(const uint4*)(vmat + row);
        const u16* kp = (const u16*)&kk;
        const u16* vp = (const u16*)&vv;
#pragma unroll
        for (int e = 0; e < 8; e++) {
            const int d = sc8 * 8 + e;
            Ak[d * 40 + scol] = kp[e];
            Bv[d * 40 + scol] = vp[e];
        }
        __syncthreads();

        bf16x8 af[2];
#pragma unroll
        for (int i = 0; i < 2; i++) {
            const int d = krow_base + i * 16 + l15;
            const int q2 = (quad ^ ((d >> 3) & 3)) * 8;
            bf16x8 raw = *(const bf16x8*)&Ak[d * 40 + q2];
            bf16x8 sc;
#pragma unroll
            for (int e = 0; e < 8; e++)
                sc[e] = (__bf16)((float)raw[e] * (use_cos ? cv[e] : sv[e]));
            af[i] = sc;
        }
        bf16x8 bfr[5];
#pragma unroll
        for (int j = 0; j < 4; j++) {
            const int n = j * 16 + l15;
            const int q2 = (quad ^ ((n >> 3) & 3)) * 8;
            bfr[j] = *(const bf16x8*)&Bv[n * 40 + q2];
        }
        bfr[4] = onesf;
#pragma unroll
        for (int i = 0; i < 2; i++)
#pragma unroll
            for (int j = 0; j < 5; j++)
                acc[i][j] = __builtin_amdgcn_mfma_f32_16x16x32_bf16(
                    af[i], bfr[j], acc[i][j], 0, 0, 0);

        // advance angles by pi/256
#pragma unroll
        for (int e = 0; e < 8; e++) {
            const float ns = sv[e] * cD + cv[e] * sD;
            cv[e] = cv[e] * cD - sv[e] * sD;
            sv[e] = ns;
        }
        __syncthreads();
    }

    float* op = part + ((long)blockIdx.x * 64 + head) * 10240;
#pragma unroll
    for (int i = 0; i < 2; i++)
#pragma unroll
        for (int j = 0; j < 5; j++)
#pragma unroll
            for (int r = 0; r < 4; r++)
                op[(mbase + i * 16 + quad * 4 + r) * 80 + j * 16 + l15] = acc[i][j][r];
}

// ---------------------------------------------------------------------------
// Stage C2: sum 8 chunk-partials, transpose to Bt[head][n=80][d2=128] bf16.
// grid (4 d2-tiles of 32, 64 heads), 256 threads.
// ---------------------------------------------------------------------------
__global__ __launch_bounds__(256) void kv_reduce_t(const float* __restrict__ part,
                                                   u16* __restrict__ Bt) {
    __shared__ float accs[32 * 81];
    const int head = blockIdx.y, d2t = blockIdx.x;
    const float* bp = part + (long)head * 10240 + d2t * 32 * 80;
    for (int idx = threadIdx.x; idx < 2560; idx += 256) {
        float s = 0.0f;
#pragma unroll
        for (int c = 0; c < 8; c++) s += bp[(long)c * 655360 + idx];
        const int d2 = idx / 80, n = idx - d2 * 80;
        accs[d2 * 81 + n] = s;
    }
    __syncthreads();
    for (int idx = threadIdx.x; idx < 2560; idx += 256) {
        const int n = idx >> 5, d2 = idx & 31;
        Bt[(long)head * 10240 + n * 128 + d2t * 32 + d2] = f32_to_bf16(accs[d2 * 81 + n]);
    }
}

// ---------------------------------------------------------------------------
// Stage D: per-head MFMA GEMM: attn[l, 0..79] = q_[l, 0..127] @ Bt^T
// ---------------------------------------------------------------------------
__global__ __launch_bounds__(256) void attn_mfma(const u16* __restrict__ qb,
                                                 const u16* __restrict__ Bt,
                                                 u16* __restrict__ merged) {
    __shared__ __align__(16) u16 As[128 * 72];   // q tile [l][64], stride 72
    __shared__ __align__(16) u16 Bs[80 * 136];   // Bt tile [n][128], stride 136
    const int tid = threadIdx.x;
    const int wave = tid >> 6, lane = tid & 63;
    const int quad = lane >> 4, l15 = lane & 15;
    const int head = blockIdx.y;
    const int b = head >> 4, h = head & 15;
    const int tm = blockIdx.x * 128;
    const long b4 = (long)b * 4096;

    for (int c = tid; c < 1024; c += 256) {
        const int row = c >> 3, c8 = c & 7;
        uint4 t = *(const uint4*)(qb + (b4 + tm + row) * 1024 + h * 64 + c8 * 8);
        *(uint4*)&As[row * 72 + c8 * 8] = t;
    }
    for (int c = tid; c < 1280; c += 256) {
        const int row = c >> 4, c16 = c & 15;
        uint4 t = *(const uint4*)(Bt + (long)head * 10240 + row * 128 + c16 * 8);
        *(uint4*)&Bs[row * 136 + c16 * 8] = t;
    }
    const int wm = wave * 32;
    float snl[2], csl[2];
#pragma unroll
    for (int i = 0; i < 2; i++) {
        const int l = tm + wm + i * 16 + l15;
        const float idx = PI_HALF * (float)(l + 1) * (1.0f / 4096.0f);
        snl[i] = sinf(idx); csl[i] = cosf(idx);
    }
    __syncthreads();

    f32x4 acc[2][5] = {};
#pragma unroll
    for (int kb = 0; kb < 4; kb++) {
        const int qc = (kb & 1) * 32 + quad * 8;
        bf16x8 af[2];
#pragma unroll
        for (int i = 0; i < 2; i++) {
            bf16x8 raw = *(const bf16x8*)&As[(wm + i * 16 + l15) * 72 + qc];
            const float s = (kb < 2) ? snl[i] : csl[i];
            bf16x8 sc;
#pragma unroll
            for (int e = 0; e < 8; e++) sc[e] = (__bf16)((float)raw[e] * s);
            af[i] = sc;
        }
        bf16x8 bf[5];
#pragma unroll
        for (int j = 0; j < 5; j++)
            bf[j] = *(const bf16x8*)&Bs[(j * 16 + l15) * 136 + kb * 32 + quad * 8];
#pragma unroll
        for (int i = 0; i < 2; i++)
#pragma unroll
            for (int j = 0; j < 5; j++)
                acc[i][j] = __builtin_amdgcn_mfma_f32_16x16x32_bf16(
                    af[i], bf[j], acc[i][j], 0, 0, 0);
    }

#pragma unroll
    for (int i = 0; i < 2; i++) {
        float z[4];
#pragma unroll
        for (int r = 0; r < 4; r++) {
            const float den = __shfl(acc[i][4][r], lane & 0x30, 64);
            z[r] = 1.0f / fmaxf(den, EPS_Z);
        }
#pragma unroll
        for (int j = 0; j < 4; j++)
#pragma unroll
            for (int r = 0; r < 4; r++) {
                const int l = tm + wm + i * 16 + quad * 4 + r;
                merged[(b4 + l) * 1024 + h * 64 + j * 16 + l15] =
                    f32_to_bf16(acc[i][j][r] * z[r]);
            }
    }
}

// ---------------------------------------------------------------------------
extern "C" void kernel_launch(void* const* d_in, const int* in_sizes, int n_in,
                              void* d_out, int out_size, void* d_ws, size_t ws_size,
                              hipStream_t stream) {
    (void)in_sizes; (void)n_in; (void)out_size; (void)ws_size;
    const float* x  = (const float*)d_in[0];
    const float* Wq = (const float*)d_in[1];
    const float* bq = (const float*)d_in[2];
    const float* Wk = (const float*)d_in[3];
    const float* bk = (const float*)d_in[4];
    const float* Wv = (const float*)d_in[5];
    const float* bv = (const float*)d_in[6];
    const float* Wo = (const float*)d_in[7];
    const float* bo = (const float*)d_in[8];
    float* out = (float*)d_out;

    const int M = 16384, E = 1024;
    char* ws = (char*)d_ws;
    const size_t MB = 1048576;
    u16* xb   = (u16*)(ws);              // 32 MiB; dead after QKV GEMM -> part
    u16* qb   = (u16*)(ws + 32 * MB);
    u16* kb   = (u16*)(ws + 64 * MB);    // dead after kv_mfma -> merged
    u16* vb   = (u16*)(ws + 96 * MB);
    u16* wcat = (u16*)(ws + 128 * MB);   // Wq;Wk;Wv;Wo bf16, 8 MiB
    u16* wob  = wcat + 3 * (size_t)E * E;
    u16* Btb  = (u16*)(ws + 136 * MB);   // 1.25 MiB
    float* part = (float*)xb;            // 8*64*10240*4 = 20 MiB
    u16* mergedb = kb;

    cvt_bf16<<<dim3(M * E / 4 / 256), dim3(256), 0, stream>>>(x, xb, M * E / 4);
    cvt_w4<<<dim3(E * E / 4 / 256, 4), dim3(256), 0, stream>>>(Wq, Wk, Wv, Wo, wcat);

    gemm_qkv<<<dim3(M / 128, 24), dim3(256), 0, stream>>>(xb, wcat, bq, bk, bv,
                                                          qb, kb, vb);

    kv_mfma<<<dim3(8, 64), dim3(256), 0, stream>>>(kb, vb, part);
    kv_reduce_t<<<dim3(4, 64), dim3(256), 0, stream>>>(part, Btb);
    attn_mfma<<<dim3(32, 64), dim3(256), 0, stream>>>(qb, Btb, mergedb);

    gemm_o<<<dim3(M / 128, E / 128), dim3(256), 0, stream>>>(mergedb, wob, bo,
                                                             out, M, E, E);
}